// Round 3
// baseline (2281.868 us; speedup 1.0000x reference)
//
#include <hip/hip_runtime.h>
#include <hip/hip_fp16.h>

#define TOTAL 131072
#define SEGN  256
#define FEAT  78
#define FPAD  96
#define HID   1024
#define NCLS  10

typedef __attribute__((ext_vector_type(8))) short short8;
typedef __attribute__((ext_vector_type(4))) float floatx4;

typedef __attribute__((address_space(1))) void gvoid_t;
typedef __attribute__((address_space(3))) void svoid_t;

__device__ __forceinline__ void async_copy16(const void* gsrc, void* ldst) {
    __builtin_amdgcn_global_load_lds((gvoid_t*)(void*)gsrc, (svoid_t*)ldst, 16, 0, 0);
}

// ---------------- conversion kernels ----------------

// x slab [rows, FEAT] fp32 -> [rows, FPAD] fp16 (zero-padded cols)
__global__ void conv_x_slab(const float* __restrict__ x, __half* __restrict__ xb,
                            int row0, int rows) {
    int idx = blockIdx.x * 256 + threadIdx.x;
    if (idx >= rows * FPAD) return;
    int col = idx % FPAD;
    int r   = idx / FPAD;
    float v = (col < FEAT) ? x[(size_t)(row0 + r) * FEAT + col] : 0.0f;
    xb[idx] = __float2half(v);
}

// W [K,N] fp32 row-major -> Wt [N,Kpad] fp16 row-major (transposed, zero-padded K)
__global__ void conv_wt_kernel(const float* __restrict__ W, __half* __restrict__ Wt,
                               int K, int N, int Kpad) {
    int idx = blockIdx.x * 256 + threadIdx.x;
    if (idx >= N * Kpad) return;
    int k = idx % Kpad;
    int n = idx / Kpad;
    float v = (k < K) ? W[(size_t)k * N + n] : 0.0f;
    Wt[idx] = __float2half(v);
}

// ---------------- main GEMM: C = act(A @ Bt^T + bias) ----------------
// A [M,K] f16 row-major, Bt [N,K] f16 row-major, C [M,N] f16, bias fp32[N]
// 128x128 tile, BK=32, 256 threads (4 waves), mfma_f32_16x16x32_f16

__global__ __launch_bounds__(256, 2)
void gemm_f16(const __half* __restrict__ A, const __half* __restrict__ Bt,
              __half* __restrict__ C, const float* __restrict__ bias,
              int M, int N, int K, int relu_flag)
{
    __shared__ __align__(16) short lds_a[128 * 32];
    __shared__ __align__(16) short lds_b[128 * 32];
    const int t    = threadIdx.x;
    const int bn   = blockIdx.x;      // N/128 (fast) -> concurrent blocks share A stripe
    const int bm   = blockIdx.y;      // M/128
    const size_t m0 = (size_t)bm * 128;
    const size_t n0 = (size_t)bn * 128;
    const int wave = t >> 6, lane = t & 63;
    const int wm = (wave >> 1) << 6;  // wave row quadrant (0/64)
    const int wn = (wave & 1) << 6;   // wave col quadrant (0/64)
    const int l16 = lane & 15, q = lane >> 4;

    floatx4 acc[4][4] = {};

    // staging chunk mapping: chunk c (16B = 8 f16): row = c>>2, k-chunk = c&3
    const int c0 = t, c1 = t + 256;
    const __half* a0 = A  + (m0 + (size_t)(c0 >> 2)) * K + (c0 & 3) * 8;
    const __half* a1 = A  + (m0 + (size_t)(c1 >> 2)) * K + (c1 & 3) * 8;
    const __half* b0 = Bt + (n0 + (size_t)(c0 >> 2)) * K + (c0 & 3) * 8;
    const __half* b1 = Bt + (n0 + (size_t)(c1 >> 2)) * K + (c1 & 3) * 8;
    short* la0 = &lds_a[c0 * 8];
    short* la1 = &lds_a[c1 * 8];
    short* lb0 = &lds_b[c0 * 8];
    short* lb1 = &lds_b[c1 * 8];

    for (int k0 = 0; k0 < K; k0 += 32) {
        __syncthreads();
        async_copy16(a0 + k0, la0);
        async_copy16(a1 + k0, la1);
        async_copy16(b0 + k0, lb0);
        async_copy16(b1 + k0, lb1);
        __syncthreads();

        short8 af[4], bf[4];
#pragma unroll
        for (int i = 0; i < 4; ++i)
            af[i] = *(const short8*)&lds_a[(wm + i * 16 + l16) * 32 + q * 8];
#pragma unroll
        for (int i = 0; i < 4; ++i)
            bf[i] = *(const short8*)&lds_b[(wn + i * 16 + l16) * 32 + q * 8];

#pragma unroll
        for (int mi = 0; mi < 4; ++mi)
#pragma unroll
            for (int ni = 0; ni < 4; ++ni)
                acc[mi][ni] = __builtin_amdgcn_mfma_f32_16x16x32_f16(
                    af[mi], bf[ni], acc[mi][ni], 0, 0, 0);
    }

    // epilogue: within a 16x16 tile: col = l16, row = q*4 + r
#pragma unroll
    for (int ni = 0; ni < 4; ++ni) {
        const int col = (int)n0 + wn + ni * 16 + l16;
        const float bv = bias[col];
#pragma unroll
        for (int mi = 0; mi < 4; ++mi) {
            const size_t row0 = m0 + wm + mi * 16 + q * 4;
#pragma unroll
            for (int r = 0; r < 4; ++r) {
                float v = acc[mi][ni][r] + bv;
                if (relu_flag) v = fmaxf(v, 0.0f);
                C[(row0 + r) * N + col] = __float2half(v);
            }
        }
    }
}

// ---------------- segment offsets ----------------

__global__ void seg_offsets_kernel(const int* __restrict__ lengths, int* __restrict__ off) {
    if (blockIdx.x == 0 && threadIdx.x == 0) {
        int a = 0;
        off[0] = 0;
        for (int i = 0; i < SEGN; ++i) { a += lengths[i]; off[i + 1] = a; }
    }
}

// ---------------- e-scores: e_f = exp(relu(h4_f . W5 + b5)) -------------------
// One wave per frame (grid = R/4 blocks x 4 waves). No max-subtract needed:
// scores >= 0 and tiny; exp(s)/sum(exp) == softmax exactly.

__global__ __launch_bounds__(256)
void escore_kernel(const __half* __restrict__ h4, int slab_beg,
                   const float* __restrict__ W5, const float* __restrict__ b5,
                   float* __restrict__ earr)
{
    const int fl   = blockIdx.x * 4 + (threadIdx.x >> 6);  // frame index within slab
    const int lane = threadIdx.x & 63;
    const __half* row = h4 + (size_t)fl * HID + lane * 16;
    const float*  wv  = W5 + lane * 16;

    short8 r0 = *(const short8*)row;
    short8 r1 = *(const short8*)(row + 8);
    float s = 0.f;
#pragma unroll
    for (int j = 0; j < 8; ++j) s += __half2float(((const __half*)&r0)[j]) * wv[j];
#pragma unroll
    for (int j = 0; j < 8; ++j) s += __half2float(((const __half*)&r1)[j]) * wv[j + 8];
#pragma unroll
    for (int o = 32; o > 0; o >>= 1) s += __shfl_down(s, o);
    if (lane == 0)
        earr[slab_beg + fl] = __expf(fminf(fmaxf(s + b5[0], 0.0f), 80.0f));
}

// ---------------- pooling accumulate (no atomics) -----------------------------
// grid (SEGN, 2): block owns segment s, columns [by*512, by*512+512).
// thread owns 2 cols (half2 loads, 256B/wave coalesced). Slabs run sequentially,
// so read-modify-write of pooled/denom is race-free.

__global__ __launch_bounds__(256)
void pool_accum_kernel(const __half* __restrict__ h4, int slab_beg, int slab_rows,
                       const float* __restrict__ earr, const int* __restrict__ segoff,
                       float* __restrict__ pooled, float* __restrict__ denom)
{
    const int s  = blockIdx.x;
    const int c0 = blockIdx.y * 512 + threadIdx.x * 2;
    int beg = segoff[s], end = segoff[s + 1];
    if (beg < slab_beg) beg = slab_beg;
    int slab_end = slab_beg + slab_rows;
    if (end > slab_end) end = slab_end;
    if (beg >= end) return;

    float a0 = 0.f, a1 = 0.f, esum = 0.f;
    const __half* base = h4 + (size_t)(beg - slab_beg) * HID + c0;
    for (int f = beg; f < end; ++f, base += HID) {
        float e = earr[f];
        float2 fv = __half22float2(*(const __half2*)base);
        a0 += e * fv.x;
        a1 += e * fv.y;
        esum += e;
    }
    float* p = pooled + (size_t)s * HID + c0;
    p[0] += a0;
    p[1] += a1;
    if (threadIdx.x == 0 && blockIdx.y == 0) denom[s] += esum;
}

// ---------------- finalize pooling: poolh = fp16(pooled / denom) --------------

__global__ void finalize_pool_kernel(const float* __restrict__ pooled_num,
                                     const float* __restrict__ denom,
                                     __half* __restrict__ poolh) {
    int s = blockIdx.x, t = threadIdx.x;
    float inv = 1.0f / denom[s];
    for (int j = t; j < HID; j += 256)
        poolh[(size_t)s * HID + j] = __float2half(pooled_num[(size_t)s * HID + j] * inv);
}

// ---------------- final head: out = z @ W7 + b7 ----------------

__global__ void final_kernel(const __half* __restrict__ z, const float* __restrict__ W7,
                             const float* __restrict__ b7, float* __restrict__ out) {
    int s = blockIdx.x, t = threadIdx.x;
    float loc[NCLS];
#pragma unroll
    for (int c = 0; c < NCLS; ++c) loc[c] = 0.f;
    for (int k = t; k < HID; k += 256) {
        float zk = __half2float(z[(size_t)s * HID + k]);
        const float* wr = W7 + k * NCLS;
#pragma unroll
        for (int c = 0; c < NCLS; ++c) loc[c] += zk * wr[c];
    }
#pragma unroll
    for (int c = 0; c < NCLS; ++c)
#pragma unroll
        for (int o = 32; o > 0; o >>= 1) loc[c] += __shfl_down(loc[c], o);
    __shared__ float accs[NCLS];
    if (t < NCLS) accs[t] = 0.f;
    __syncthreads();
    if ((t & 63) == 0)
        for (int c = 0; c < NCLS; ++c) atomicAdd(&accs[c], loc[c]);
    __syncthreads();
    if (t < NCLS) out[s * NCLS + t] = accs[t] + b7[t];
}

// ---------------- launch ----------------

extern "C" void kernel_launch(void* const* d_in, const int* in_sizes, int n_in,
                              void* d_out, int out_size, void* d_ws, size_t ws_size,
                              hipStream_t stream) {
    const float* x  = (const float*)d_in[0];
    const float* W1 = (const float*)d_in[1];
    const float* b1 = (const float*)d_in[2];
    const float* W2 = (const float*)d_in[3];
    const float* b2 = (const float*)d_in[4];
    const float* W3 = (const float*)d_in[5];
    const float* b3 = (const float*)d_in[6];
    const float* W4 = (const float*)d_in[7];
    const float* b4 = (const float*)d_in[8];
    const float* W5 = (const float*)d_in[9];
    const float* b5 = (const float*)d_in[10];
    const float* W6 = (const float*)d_in[11];
    const float* b6 = (const float*)d_in[12];
    const float* W7 = (const float*)d_in[13];
    const float* b7 = (const float*)d_in[14];
    const int* lengths = (const int*)d_in[15];
    float* out = (float*)d_out;

    // ---- adaptive workspace layout (same arithmetic every call -> capture-safe) ----
    char* ws = (char*)d_ws;
    size_t off = 0;
    auto take = [&](size_t bytes) -> char* {
        char* p = ws + off;
        off = (off + bytes + 255) & ~(size_t)255;
        return p;
    };
    __half* w1t   = (__half*)take((size_t)HID * FPAD * 2);
    __half* w2t   = (__half*)take((size_t)HID * HID * 2);
    __half* w3t   = (__half*)take((size_t)HID * HID * 2);
    __half* w4t   = (__half*)take((size_t)HID * HID * 2);
    __half* w6t   = (__half*)take((size_t)HID * HID * 2);
    int*    segoff = (int*)take((SEGN + 1) * 4);
    float*  pooled = (float*)take((size_t)SEGN * HID * 4);
    float*  denom  = (float*)take(SEGN * 4);
    __half* poolh  = (__half*)take((size_t)SEGN * HID * 2);
    __half* z      = (__half*)take((size_t)SEGN * HID * 2);
    float*  earr   = (float*)take((size_t)TOTAL * 4);

    // slab rows: largest power-of-two divisor of TOTAL that fits
    int R = TOTAL;
    while (R > 1024) {
        size_t need = off + (size_t)R * FPAD * 2 + 2 * (size_t)R * HID * 2 + 3 * 256;
        if (need <= ws_size) break;
        R >>= 1;
    }
    __half* slabX = (__half*)take((size_t)R * FPAD * 2);
    __half* slabA = (__half*)take((size_t)R * HID * 2);
    __half* slabB = (__half*)take((size_t)R * HID * 2);

    // ---- preliminaries ----
    seg_offsets_kernel<<<1, 64, 0, stream>>>(lengths, segoff);
    hipMemsetAsync(pooled, 0, (size_t)SEGN * HID * 4, stream);
    hipMemsetAsync(denom, 0, SEGN * 4, stream);

    conv_wt_kernel<<<(HID * FPAD + 255) / 256, 256, 0, stream>>>(W1, w1t, FEAT, HID, FPAD);
    conv_wt_kernel<<<(HID * HID + 255) / 256, 256, 0, stream>>>(W2, w2t, HID, HID, HID);
    conv_wt_kernel<<<(HID * HID + 255) / 256, 256, 0, stream>>>(W3, w3t, HID, HID, HID);
    conv_wt_kernel<<<(HID * HID + 255) / 256, 256, 0, stream>>>(W4, w4t, HID, HID, HID);
    conv_wt_kernel<<<(HID * HID + 255) / 256, 256, 0, stream>>>(W6, w6t, HID, HID, HID);

    // ---- slabbed trunk + score + pool ----
    dim3 gSlab(HID / 128, R / 128);
    dim3 gPool(SEGN, 2);
    for (int sb = 0; sb < TOTAL; sb += R) {
        conv_x_slab<<<(R * FPAD + 255) / 256, 256, 0, stream>>>(x, slabX, sb, R);
        gemm_f16<<<gSlab, 256, 0, stream>>>(slabX, w1t, slabA, b1, R, HID, FPAD, 1);
        gemm_f16<<<gSlab, 256, 0, stream>>>(slabA, w2t, slabB, b2, R, HID, HID, 1);
        gemm_f16<<<gSlab, 256, 0, stream>>>(slabB, w3t, slabA, b3, R, HID, HID, 1);
        gemm_f16<<<gSlab, 256, 0, stream>>>(slabA, w4t, slabB, b4, R, HID, HID, 1);   // h4
        escore_kernel<<<R / 4, 256, 0, stream>>>(slabB, sb, W5, b5, earr);
        pool_accum_kernel<<<gPool, 256, 0, stream>>>(slabB, sb, R, earr, segoff, pooled, denom);
    }

    // ---- head ----
    finalize_pool_kernel<<<SEGN, 256, 0, stream>>>(pooled, denom, poolh);
    dim3 gHead(HID / 128, SEGN / 128);
    gemm_f16<<<gHead, 256, 0, stream>>>(poolh, w6t, z, b6, SEGN, HID, HID, 1);
    final_kernel<<<SEGN, 256, 0, stream>>>(z, W7, b7, out);
}

// Round 4
// 1559.617 us; speedup vs baseline: 1.4631x; 1.4631x over previous
//
#include <hip/hip_runtime.h>
#include <hip/hip_fp16.h>

#define TOTAL 131072
#define SEGN  256
#define FEAT  78
#define FPAD  96
#define HID   1024
#define NCLS  10
#define FCHUNK 32

typedef __attribute__((ext_vector_type(8))) short short8;
typedef __attribute__((ext_vector_type(4))) float floatx4;

typedef __attribute__((address_space(1))) void gvoid_t;
typedef __attribute__((address_space(3))) void svoid_t;

__device__ __forceinline__ void async_copy16(const void* gsrc, void* ldst) {
    __builtin_amdgcn_global_load_lds((gvoid_t*)(void*)gsrc, (svoid_t*)ldst, 16, 0, 0);
}

// ---------------- conversion kernels ----------------

__global__ void conv_x_slab(const float* __restrict__ x, __half* __restrict__ xb,
                            int row0, int rows) {
    int idx = blockIdx.x * 256 + threadIdx.x;
    if (idx >= rows * FPAD) return;
    int col = idx % FPAD;
    int r   = idx / FPAD;
    float v = (col < FEAT) ? x[(size_t)(row0 + r) * FEAT + col] : 0.0f;
    xb[idx] = __float2half(v);
}

// W [K,N] fp32 row-major -> Wt [N,Kpad] fp16 row-major (transposed, zero-padded K)
__global__ void conv_wt_kernel(const float* __restrict__ W, __half* __restrict__ Wt,
                               int K, int N, int Kpad) {
    int idx = blockIdx.x * 256 + threadIdx.x;
    if (idx >= N * Kpad) return;
    int k = idx % Kpad;
    int n = idx / Kpad;
    float v = (k < K) ? W[(size_t)k * N + n] : 0.0f;
    Wt[idx] = __float2half(v);
}

// ---------------- main GEMM: C = act(A @ Bt^T + bias) ----------------
// A [M,K] f16 row-major, Bt [N,K] f16 row-major, C [M,N] f16, bias fp32[N]
// 128x128 tile, BK=32, 256 threads (4 waves), mfma_f32_16x16x32_f16

__global__ __launch_bounds__(256, 2)
void gemm_f16(const __half* __restrict__ A, const __half* __restrict__ Bt,
              __half* __restrict__ C, const float* __restrict__ bias,
              int M, int N, int K, int relu_flag)
{
    __shared__ __align__(16) short lds_a[128 * 32];
    __shared__ __align__(16) short lds_b[128 * 32];
    const int t    = threadIdx.x;
    const int bn   = blockIdx.x;
    const int bm   = blockIdx.y;
    const size_t m0 = (size_t)bm * 128;
    const size_t n0 = (size_t)bn * 128;
    const int wave = t >> 6, lane = t & 63;
    const int wm = (wave >> 1) << 6;
    const int wn = (wave & 1) << 6;
    const int l16 = lane & 15, q = lane >> 4;

    floatx4 acc[4][4] = {};

    const int c0 = t, c1 = t + 256;
    const __half* a0 = A  + (m0 + (size_t)(c0 >> 2)) * K + (c0 & 3) * 8;
    const __half* a1 = A  + (m0 + (size_t)(c1 >> 2)) * K + (c1 & 3) * 8;
    const __half* b0 = Bt + (n0 + (size_t)(c0 >> 2)) * K + (c0 & 3) * 8;
    const __half* b1 = Bt + (n0 + (size_t)(c1 >> 2)) * K + (c1 & 3) * 8;
    short* la0 = &lds_a[c0 * 8];
    short* la1 = &lds_a[c1 * 8];
    short* lb0 = &lds_b[c0 * 8];
    short* lb1 = &lds_b[c1 * 8];

    for (int k0 = 0; k0 < K; k0 += 32) {
        __syncthreads();
        async_copy16(a0 + k0, la0);
        async_copy16(a1 + k0, la1);
        async_copy16(b0 + k0, lb0);
        async_copy16(b1 + k0, lb1);
        __syncthreads();

        short8 af[4], bf[4];
#pragma unroll
        for (int i = 0; i < 4; ++i)
            af[i] = *(const short8*)&lds_a[(wm + i * 16 + l16) * 32 + q * 8];
#pragma unroll
        for (int i = 0; i < 4; ++i)
            bf[i] = *(const short8*)&lds_b[(wn + i * 16 + l16) * 32 + q * 8];

#pragma unroll
        for (int mi = 0; mi < 4; ++mi)
#pragma unroll
            for (int ni = 0; ni < 4; ++ni)
                acc[mi][ni] = __builtin_amdgcn_mfma_f32_16x16x32_f16(
                    af[mi], bf[ni], acc[mi][ni], 0, 0, 0);
    }

#pragma unroll
    for (int ni = 0; ni < 4; ++ni) {
        const int col = (int)n0 + wn + ni * 16 + l16;
        const float bv = bias[col];
#pragma unroll
        for (int mi = 0; mi < 4; ++mi) {
            const size_t row0 = m0 + wm + mi * 16 + q * 4;
#pragma unroll
            for (int r = 0; r < 4; ++r) {
                float v = acc[mi][ni][r] + bv;
                if (relu_flag) v = fmaxf(v, 0.0f);
                C[(row0 + r) * N + col] = __float2half(v);
            }
        }
    }
}

// ---------------- segment offsets ----------------

__global__ void seg_offsets_kernel(const int* __restrict__ lengths, int* __restrict__ off) {
    if (blockIdx.x == 0 && threadIdx.x == 0) {
        int a = 0;
        off[0] = 0;
        for (int i = 0; i < SEGN; ++i) { a += lengths[i]; off[i + 1] = a; }
    }
}

// ---------------- e-scores: e_f = exp(relu(h4_f . W5 + b5)) -------------------
// One wave per frame. scores >= 0 and small -> exp without max-subtract is the
// exact softmax numerator.

__global__ __launch_bounds__(256)
void escore_kernel(const __half* __restrict__ h4, int slab_beg,
                   const float* __restrict__ W5, const float* __restrict__ b5,
                   float* __restrict__ earr)
{
    const int fl   = blockIdx.x * 4 + (threadIdx.x >> 6);
    const int lane = threadIdx.x & 63;
    const __half* row = h4 + (size_t)fl * HID + lane * 16;
    const float*  wv  = W5 + lane * 16;

    short8 r0 = *(const short8*)row;
    short8 r1 = *(const short8*)(row + 8);
    float s = 0.f;
#pragma unroll
    for (int j = 0; j < 8; ++j) s += __half2float(((const __half*)&r0)[j]) * wv[j];
#pragma unroll
    for (int j = 0; j < 8; ++j) s += __half2float(((const __half*)&r1)[j]) * wv[j + 8];
#pragma unroll
    for (int o = 32; o > 0; o >>= 1) s += __shfl_down(s, o);
    if (lane == 0)
        earr[slab_beg + fl] = __expf(fminf(fmaxf(s + b5[0], 0.0f), 80.0f));
}

// ---------------- pooling accumulate: frame-chunk parallel --------------------
// grid (R/FCHUNK, 2). Block owns FCHUNK frames x 512 cols (thread = 2 cols).
// A 32-frame chunk crosses at most 2 segments (min seg length ~256); accumulate
// per segment-span in registers, one atomicAdd flush per span.

__global__ __launch_bounds__(256)
void pool_accum_kernel(const __half* __restrict__ h4, int slab_beg,
                       const float* __restrict__ earr, const int* __restrict__ segoff,
                       float* __restrict__ pooled)
{
    const int c0 = blockIdx.y * 512 + threadIdx.x * 2;
    const int f0 = slab_beg + blockIdx.x * FCHUNK;   // global frame
    const int fend = f0 + FCHUNK;

    // uniform binary search: s with segoff[s] <= f0 < segoff[s+1]
    int lo = 0, hi = SEGN - 1;
    while (lo < hi) {
        int mid = (lo + hi + 1) >> 1;
        if (segoff[mid] <= f0) lo = mid; else hi = mid - 1;
    }
    int s = lo;

    const __half* base = h4 + (size_t)(f0 - slab_beg) * HID + c0;
    int f = f0;
    while (f < fend) {
        int send = segoff[s + 1];
        if (send > fend) send = fend;
        float a0 = 0.f, a1 = 0.f;
        for (; f < send; ++f, base += HID) {
            float e = earr[f];
            float2 fv = __half22float2(*(const __half2*)base);
            a0 += e * fv.x;
            a1 += e * fv.y;
        }
        float* p = pooled + (size_t)s * HID + c0;
        atomicAdd(p, a0);
        atomicAdd(p + 1, a1);
        ++s;
    }
}

// ---------------- finalize: denom reduce + divide + fp16 ----------------------

__global__ __launch_bounds__(256)
void finalize_pool_kernel(const float* __restrict__ pooled, const float* __restrict__ earr,
                          const int* __restrict__ segoff, __half* __restrict__ poolh)
{
    int s = blockIdx.x, t = threadIdx.x;
    int beg = segoff[s], end = segoff[s + 1];
    __shared__ float sh[4];
    float es = 0.f;
    for (int i = beg + t; i < end; i += 256) es += earr[i];
#pragma unroll
    for (int o = 32; o > 0; o >>= 1) es += __shfl_down(es, o);
    if ((t & 63) == 0) sh[t >> 6] = es;
    __syncthreads();
    float inv = 1.0f / (sh[0] + sh[1] + sh[2] + sh[3]);
    for (int j = t; j < HID; j += 256)
        poolh[(size_t)s * HID + j] = __float2half(pooled[(size_t)s * HID + j] * inv);
}

// ---------------- final head: out = z @ W7 + b7 ----------------

__global__ void final_kernel(const __half* __restrict__ z, const float* __restrict__ W7,
                             const float* __restrict__ b7, float* __restrict__ out) {
    int s = blockIdx.x, t = threadIdx.x;
    float loc[NCLS];
#pragma unroll
    for (int c = 0; c < NCLS; ++c) loc[c] = 0.f;
    for (int k = t; k < HID; k += 256) {
        float zk = __half2float(z[(size_t)s * HID + k]);
        const float* wr = W7 + k * NCLS;
#pragma unroll
        for (int c = 0; c < NCLS; ++c) loc[c] += zk * wr[c];
    }
#pragma unroll
    for (int c = 0; c < NCLS; ++c)
#pragma unroll
        for (int o = 32; o > 0; o >>= 1) loc[c] += __shfl_down(loc[c], o);
    __shared__ float accs[NCLS];
    if (t < NCLS) accs[t] = 0.f;
    __syncthreads();
    if ((t & 63) == 0)
        for (int c = 0; c < NCLS; ++c) atomicAdd(&accs[c], loc[c]);
    __syncthreads();
    if (t < NCLS) out[s * NCLS + t] = accs[t] + b7[t];
}

// ---------------- launch ----------------

extern "C" void kernel_launch(void* const* d_in, const int* in_sizes, int n_in,
                              void* d_out, int out_size, void* d_ws, size_t ws_size,
                              hipStream_t stream) {
    const float* x  = (const float*)d_in[0];
    const float* W1 = (const float*)d_in[1];
    const float* b1 = (const float*)d_in[2];
    const float* W2 = (const float*)d_in[3];
    const float* b2 = (const float*)d_in[4];
    const float* W3 = (const float*)d_in[5];
    const float* b3 = (const float*)d_in[6];
    const float* W4 = (const float*)d_in[7];
    const float* b4 = (const float*)d_in[8];
    const float* W5 = (const float*)d_in[9];
    const float* b5 = (const float*)d_in[10];
    const float* W6 = (const float*)d_in[11];
    const float* b6 = (const float*)d_in[12];
    const float* W7 = (const float*)d_in[13];
    const float* b7 = (const float*)d_in[14];
    const int* lengths = (const int*)d_in[15];
    float* out = (float*)d_out;

    char* ws = (char*)d_ws;
    size_t off = 0;
    auto take = [&](size_t bytes) -> char* {
        char* p = ws + off;
        off = (off + bytes + 255) & ~(size_t)255;
        return p;
    };
    __half* w1t   = (__half*)take((size_t)HID * FPAD * 2);
    __half* w2t   = (__half*)take((size_t)HID * HID * 2);
    __half* w3t   = (__half*)take((size_t)HID * HID * 2);
    __half* w4t   = (__half*)take((size_t)HID * HID * 2);
    __half* w6t   = (__half*)take((size_t)HID * HID * 2);
    int*    segoff = (int*)take((SEGN + 1) * 4);
    float*  pooled = (float*)take((size_t)SEGN * HID * 4);
    __half* poolh  = (__half*)take((size_t)SEGN * HID * 2);
    __half* z      = (__half*)take((size_t)SEGN * HID * 2);
    float*  earr   = (float*)take((size_t)TOTAL * 4);

    int R = TOTAL;
    while (R > 1024) {
        size_t need = off + (size_t)R * FPAD * 2 + 2 * (size_t)R * HID * 2 + 3 * 256;
        if (need <= ws_size) break;
        R >>= 1;
    }
    __half* slabX = (__half*)take((size_t)R * FPAD * 2);
    __half* slabA = (__half*)take((size_t)R * HID * 2);
    __half* slabB = (__half*)take((size_t)R * HID * 2);

    seg_offsets_kernel<<<1, 64, 0, stream>>>(lengths, segoff);
    hipMemsetAsync(pooled, 0, (size_t)SEGN * HID * 4, stream);

    conv_wt_kernel<<<(HID * FPAD + 255) / 256, 256, 0, stream>>>(W1, w1t, FEAT, HID, FPAD);
    conv_wt_kernel<<<(HID * HID + 255) / 256, 256, 0, stream>>>(W2, w2t, HID, HID, HID);
    conv_wt_kernel<<<(HID * HID + 255) / 256, 256, 0, stream>>>(W3, w3t, HID, HID, HID);
    conv_wt_kernel<<<(HID * HID + 255) / 256, 256, 0, stream>>>(W4, w4t, HID, HID, HID);
    conv_wt_kernel<<<(HID * HID + 255) / 256, 256, 0, stream>>>(W6, w6t, HID, HID, HID);

    dim3 gSlab(HID / 128, R / 128);
    dim3 gPool(R / FCHUNK, 2);
    for (int sb = 0; sb < TOTAL; sb += R) {
        conv_x_slab<<<(R * FPAD + 255) / 256, 256, 0, stream>>>(x, slabX, sb, R);
        gemm_f16<<<gSlab, 256, 0, stream>>>(slabX, w1t, slabA, b1, R, HID, FPAD, 1);
        gemm_f16<<<gSlab, 256, 0, stream>>>(slabA, w2t, slabB, b2, R, HID, HID, 1);
        gemm_f16<<<gSlab, 256, 0, stream>>>(slabB, w3t, slabA, b3, R, HID, HID, 1);
        gemm_f16<<<gSlab, 256, 0, stream>>>(slabA, w4t, slabB, b4, R, HID, HID, 1);
        escore_kernel<<<R / 4, 256, 0, stream>>>(slabB, sb, W5, b5, earr);
        pool_accum_kernel<<<gPool, 256, 0, stream>>>(slabB, sb, earr, segoff, pooled);
    }

    finalize_pool_kernel<<<SEGN, 256, 0, stream>>>(pooled, earr, segoff, poolh);
    dim3 gHead(HID / 128, SEGN / 128);
    gemm_f16<<<gHead, 256, 0, stream>>>(poolh, w6t, z, b6, SEGN, HID, HID, 1);
    final_kernel<<<SEGN, 256, 0, stream>>>(z, W7, b7, out);
}

// Round 5
// 1369.332 us; speedup vs baseline: 1.6664x; 1.1390x over previous
//
#include <hip/hip_runtime.h>
#include <hip/hip_fp16.h>

#define TOTAL 131072
#define SEGN  256
#define FEAT  78
#define FPAD  96
#define HID   1024
#define NCLS  10
#define FCHUNK 32

typedef __attribute__((ext_vector_type(8))) short short8;
typedef __attribute__((ext_vector_type(4))) float floatx4;

typedef __attribute__((address_space(1))) void gvoid_t;
typedef __attribute__((address_space(3))) void svoid_t;

__device__ __forceinline__ void async_copy16(const void* gsrc, void* ldst) {
    __builtin_amdgcn_global_load_lds((gvoid_t*)(void*)gsrc, (svoid_t*)ldst, 16, 0, 0);
}

// ---------------- conversion kernels ----------------

__global__ void conv_x_slab(const float* __restrict__ x, __half* __restrict__ xb,
                            int row0, int rows) {
    int idx = blockIdx.x * 256 + threadIdx.x;
    if (idx >= rows * FPAD) return;
    int col = idx % FPAD;
    int r   = idx / FPAD;
    float v = (col < FEAT) ? x[(size_t)(row0 + r) * FEAT + col] : 0.0f;
    xb[idx] = __float2half(v);
}

// W [K,N] fp32 row-major -> Wt [N,Kpad] fp16 row-major (transposed, zero-padded K)
__global__ void conv_wt_kernel(const float* __restrict__ W, __half* __restrict__ Wt,
                               int K, int N, int Kpad) {
    int idx = blockIdx.x * 256 + threadIdx.x;
    if (idx >= N * Kpad) return;
    int k = idx % Kpad;
    int n = idx / Kpad;
    float v = (k < K) ? W[(size_t)k * N + n] : 0.0f;
    Wt[idx] = __float2half(v);
}

// ---------------- main GEMM: C = act(A @ Bt^T + bias) ----------------
// A [M,K] f16 row-major, Bt [N,K] f16 row-major, C [M,N] f16, bias fp32[N]
// 128x128 tile, BK=32, 256 threads (4 waves), mfma_f32_16x16x32_f16.
// 1D grid + XCD-aware swizzle: bm-space partitioned across the 8 XCDs so each
// A-stripe is consumed by exactly one XCD's L2 (blocks b%8 -> XCD b%8).

__global__ __launch_bounds__(256, 2)
void gemm_f16(const __half* __restrict__ A, const __half* __restrict__ Bt,
              __half* __restrict__ C, const float* __restrict__ bias,
              int M, int N, int K, int relu_flag)
{
    __shared__ __align__(16) short lds_a[128 * 32];
    __shared__ __align__(16) short lds_b[128 * 32];
    const int t   = threadIdx.x;
    const int nbn = N >> 7;
    const int nbm = M >> 7;
    int bm, bn;
    {
        const int b = blockIdx.x;
        if ((nbm & 7) == 0) {
            const int xcd = b & 7;
            const int j   = b >> 3;
            bm = xcd * (nbm >> 3) + j / nbn;   // contiguous bm range per XCD
            bn = j % nbn;                      // bn-fast within XCD -> A-stripe reuse
        } else {
            bn = b % nbn;
            bm = b / nbn;
        }
    }
    const size_t m0 = (size_t)bm * 128;
    const size_t n0 = (size_t)bn * 128;
    const int wave = t >> 6, lane = t & 63;
    const int wm = (wave >> 1) << 6;
    const int wn = (wave & 1) << 6;
    const int l16 = lane & 15, q = lane >> 4;

    floatx4 acc[4][4] = {};

    const int c0 = t, c1 = t + 256;
    const __half* a0 = A  + (m0 + (size_t)(c0 >> 2)) * K + (c0 & 3) * 8;
    const __half* a1 = A  + (m0 + (size_t)(c1 >> 2)) * K + (c1 & 3) * 8;
    const __half* b0 = Bt + (n0 + (size_t)(c0 >> 2)) * K + (c0 & 3) * 8;
    const __half* b1 = Bt + (n0 + (size_t)(c1 >> 2)) * K + (c1 & 3) * 8;
    short* la0 = &lds_a[c0 * 8];
    short* la1 = &lds_a[c1 * 8];
    short* lb0 = &lds_b[c0 * 8];
    short* lb1 = &lds_b[c1 * 8];

    for (int k0 = 0; k0 < K; k0 += 32) {
        __syncthreads();
        async_copy16(a0 + k0, la0);
        async_copy16(a1 + k0, la1);
        async_copy16(b0 + k0, lb0);
        async_copy16(b1 + k0, lb1);
        __syncthreads();

        short8 af[4], bf[4];
#pragma unroll
        for (int i = 0; i < 4; ++i)
            af[i] = *(const short8*)&lds_a[(wm + i * 16 + l16) * 32 + q * 8];
#pragma unroll
        for (int i = 0; i < 4; ++i)
            bf[i] = *(const short8*)&lds_b[(wn + i * 16 + l16) * 32 + q * 8];

#pragma unroll
        for (int mi = 0; mi < 4; ++mi)
#pragma unroll
            for (int ni = 0; ni < 4; ++ni)
                acc[mi][ni] = __builtin_amdgcn_mfma_f32_16x16x32_f16(
                    af[mi], bf[ni], acc[mi][ni], 0, 0, 0);
    }

#pragma unroll
    for (int ni = 0; ni < 4; ++ni) {
        const int col = (int)n0 + wn + ni * 16 + l16;
        const float bv = bias[col];
#pragma unroll
        for (int mi = 0; mi < 4; ++mi) {
            const size_t row0 = m0 + wm + mi * 16 + q * 4;
#pragma unroll
            for (int r = 0; r < 4; ++r) {
                float v = acc[mi][ni][r] + bv;
                if (relu_flag) v = fmaxf(v, 0.0f);
                C[(row0 + r) * N + col] = __float2half(v);
            }
        }
    }
}

// ---------------- segment offsets ----------------

__global__ void seg_offsets_kernel(const int* __restrict__ lengths, int* __restrict__ off) {
    if (blockIdx.x == 0 && threadIdx.x == 0) {
        int a = 0;
        off[0] = 0;
        for (int i = 0; i < SEGN; ++i) { a += lengths[i]; off[i + 1] = a; }
    }
}

// ---------------- e-scores: e_f = exp(relu(h4_f . W5 + b5)) -------------------

__global__ __launch_bounds__(256)
void escore_kernel(const __half* __restrict__ h4, int slab_beg,
                   const float* __restrict__ W5, const float* __restrict__ b5,
                   float* __restrict__ earr)
{
    const int fl   = blockIdx.x * 4 + (threadIdx.x >> 6);
    const int lane = threadIdx.x & 63;
    const __half* row = h4 + (size_t)fl * HID + lane * 16;
    const float*  wv  = W5 + lane * 16;

    short8 r0 = *(const short8*)row;
    short8 r1 = *(const short8*)(row + 8);
    float s = 0.f;
#pragma unroll
    for (int j = 0; j < 8; ++j) s += __half2float(((const __half*)&r0)[j]) * wv[j];
#pragma unroll
    for (int j = 0; j < 8; ++j) s += __half2float(((const __half*)&r1)[j]) * wv[j + 8];
#pragma unroll
    for (int o = 32; o > 0; o >>= 1) s += __shfl_down(s, o);
    if (lane == 0)
        earr[slab_beg + fl] = __expf(fminf(fmaxf(s + b5[0], 0.0f), 80.0f));
}

// ---------------- pooling accumulate: frame-chunk parallel --------------------

__global__ __launch_bounds__(256)
void pool_accum_kernel(const __half* __restrict__ h4, int slab_beg,
                       const float* __restrict__ earr, const int* __restrict__ segoff,
                       float* __restrict__ pooled)
{
    const int c0 = blockIdx.y * 512 + threadIdx.x * 2;
    const int f0 = slab_beg + blockIdx.x * FCHUNK;
    const int fend = f0 + FCHUNK;

    int lo = 0, hi = SEGN - 1;
    while (lo < hi) {
        int mid = (lo + hi + 1) >> 1;
        if (segoff[mid] <= f0) lo = mid; else hi = mid - 1;
    }
    int s = lo;

    const __half* base = h4 + (size_t)(f0 - slab_beg) * HID + c0;
    int f = f0;
    while (f < fend) {
        int send = segoff[s + 1];
        if (send > fend) send = fend;
        float a0 = 0.f, a1 = 0.f;
        for (; f < send; ++f, base += HID) {
            float e = earr[f];
            float2 fv = __half22float2(*(const __half2*)base);
            a0 += e * fv.x;
            a1 += e * fv.y;
        }
        float* p = pooled + (size_t)s * HID + c0;
        atomicAdd(p, a0);
        atomicAdd(p + 1, a1);
        ++s;
    }
}

// ---------------- finalize: denom reduce + divide + fp16 ----------------------

__global__ __launch_bounds__(256)
void finalize_pool_kernel(const float* __restrict__ pooled, const float* __restrict__ earr,
                          const int* __restrict__ segoff, __half* __restrict__ poolh)
{
    int s = blockIdx.x, t = threadIdx.x;
    int beg = segoff[s], end = segoff[s + 1];
    __shared__ float sh[4];
    float es = 0.f;
    for (int i = beg + t; i < end; i += 256) es += earr[i];
#pragma unroll
    for (int o = 32; o > 0; o >>= 1) es += __shfl_down(es, o);
    if ((t & 63) == 0) sh[t >> 6] = es;
    __syncthreads();
    float inv = 1.0f / (sh[0] + sh[1] + sh[2] + sh[3]);
    for (int j = t; j < HID; j += 256)
        poolh[(size_t)s * HID + j] = __float2half(pooled[(size_t)s * HID + j] * inv);
}

// ---------------- final head: out = z @ W7 + b7 ----------------

__global__ void final_kernel(const __half* __restrict__ z, const float* __restrict__ W7,
                             const float* __restrict__ b7, float* __restrict__ out) {
    int s = blockIdx.x, t = threadIdx.x;
    float loc[NCLS];
#pragma unroll
    for (int c = 0; c < NCLS; ++c) loc[c] = 0.f;
    for (int k = t; k < HID; k += 256) {
        float zk = __half2float(z[(size_t)s * HID + k]);
        const float* wr = W7 + k * NCLS;
#pragma unroll
        for (int c = 0; c < NCLS; ++c) loc[c] += zk * wr[c];
    }
#pragma unroll
    for (int c = 0; c < NCLS; ++c)
#pragma unroll
        for (int o = 32; o > 0; o >>= 1) loc[c] += __shfl_down(loc[c], o);
    __shared__ float accs[NCLS];
    if (t < NCLS) accs[t] = 0.f;
    __syncthreads();
    if ((t & 63) == 0)
        for (int c = 0; c < NCLS; ++c) atomicAdd(&accs[c], loc[c]);
    __syncthreads();
    if (t < NCLS) out[s * NCLS + t] = accs[t] + b7[t];
}

// ---------------- launch ----------------

extern "C" void kernel_launch(void* const* d_in, const int* in_sizes, int n_in,
                              void* d_out, int out_size, void* d_ws, size_t ws_size,
                              hipStream_t stream) {
    const float* x  = (const float*)d_in[0];
    const float* W1 = (const float*)d_in[1];
    const float* b1 = (const float*)d_in[2];
    const float* W2 = (const float*)d_in[3];
    const float* b2 = (const float*)d_in[4];
    const float* W3 = (const float*)d_in[5];
    const float* b3 = (const float*)d_in[6];
    const float* W4 = (const float*)d_in[7];
    const float* b4 = (const float*)d_in[8];
    const float* W5 = (const float*)d_in[9];
    const float* b5 = (const float*)d_in[10];
    const float* W6 = (const float*)d_in[11];
    const float* b6 = (const float*)d_in[12];
    const float* W7 = (const float*)d_in[13];
    const float* b7 = (const float*)d_in[14];
    const int* lengths = (const int*)d_in[15];
    float* out = (float*)d_out;

    char* ws = (char*)d_ws;
    size_t off = 0;
    auto take = [&](size_t bytes) -> char* {
        char* p = ws + off;
        off = (off + bytes + 255) & ~(size_t)255;
        return p;
    };
    __half* w1t   = (__half*)take((size_t)HID * FPAD * 2);
    __half* w2t   = (__half*)take((size_t)HID * HID * 2);
    __half* w3t   = (__half*)take((size_t)HID * HID * 2);
    __half* w4t   = (__half*)take((size_t)HID * HID * 2);
    __half* w6t   = (__half*)take((size_t)HID * HID * 2);
    int*    segoff = (int*)take((SEGN + 1) * 4);
    float*  pooled = (float*)take((size_t)SEGN * HID * 4);
    __half* poolh  = (__half*)take((size_t)SEGN * HID * 2);
    __half* z      = (__half*)take((size_t)SEGN * HID * 2);
    float*  earr   = (float*)take((size_t)TOTAL * 4);

    int R = TOTAL;
    while (R > 1024) {
        size_t need = off + (size_t)R * FPAD * 2 + 2 * (size_t)R * HID * 2 + 3 * 256;
        if (need <= ws_size) break;
        R >>= 1;
    }
    __half* slabX = (__half*)take((size_t)R * FPAD * 2);
    __half* slabA = (__half*)take((size_t)R * HID * 2);
    __half* slabB = (__half*)take((size_t)R * HID * 2);

    seg_offsets_kernel<<<1, 64, 0, stream>>>(lengths, segoff);
    hipMemsetAsync(pooled, 0, (size_t)SEGN * HID * 4, stream);

    conv_wt_kernel<<<(HID * FPAD + 255) / 256, 256, 0, stream>>>(W1, w1t, FEAT, HID, FPAD);
    conv_wt_kernel<<<(HID * HID + 255) / 256, 256, 0, stream>>>(W2, w2t, HID, HID, HID);
    conv_wt_kernel<<<(HID * HID + 255) / 256, 256, 0, stream>>>(W3, w3t, HID, HID, HID);
    conv_wt_kernel<<<(HID * HID + 255) / 256, 256, 0, stream>>>(W4, w4t, HID, HID, HID);
    conv_wt_kernel<<<(HID * HID + 255) / 256, 256, 0, stream>>>(W6, w6t, HID, HID, HID);

    const int nBlocksSlab = (R / 128) * (HID / 128);
    dim3 gPool(R / FCHUNK, 2);
    for (int sb = 0; sb < TOTAL; sb += R) {
        conv_x_slab<<<(R * FPAD + 255) / 256, 256, 0, stream>>>(x, slabX, sb, R);
        gemm_f16<<<nBlocksSlab, 256, 0, stream>>>(slabX, w1t, slabA, b1, R, HID, FPAD, 1);
        gemm_f16<<<nBlocksSlab, 256, 0, stream>>>(slabA, w2t, slabB, b2, R, HID, HID, 1);
        gemm_f16<<<nBlocksSlab, 256, 0, stream>>>(slabB, w3t, slabA, b3, R, HID, HID, 1);
        gemm_f16<<<nBlocksSlab, 256, 0, stream>>>(slabA, w4t, slabB, b4, R, HID, HID, 1);
        escore_kernel<<<R / 4, 256, 0, stream>>>(slabB, sb, W5, b5, earr);
        pool_accum_kernel<<<gPool, 256, 0, stream>>>(slabB, sb, earr, segoff, pooled);
    }

    finalize_pool_kernel<<<SEGN, 256, 0, stream>>>(pooled, earr, segoff, poolh);
    const int nBlocksHead = (SEGN / 128) * (HID / 128);
    gemm_f16<<<nBlocksHead, 256, 0, stream>>>(poolh, w6t, z, b6, SEGN, HID, HID, 1);
    final_kernel<<<SEGN, 256, 0, stream>>>(z, W7, b7, out);
}

// Round 6
// 1335.757 us; speedup vs baseline: 1.7083x; 1.0251x over previous
//
#include <hip/hip_runtime.h>
#include <hip/hip_fp16.h>

#define TOTAL 131072
#define SEGN  256
#define FEAT  78
#define FPAD  96
#define HID   1024
#define NCLS  10
#define FCHUNK 32

typedef __attribute__((ext_vector_type(8))) short short8;
typedef __attribute__((ext_vector_type(4))) float floatx4;

typedef __attribute__((address_space(1))) void gvoid_t;
typedef __attribute__((address_space(3))) void svoid_t;

__device__ __forceinline__ void async_copy16(const void* gsrc, void* ldst) {
    __builtin_amdgcn_global_load_lds((gvoid_t*)(void*)gsrc, (svoid_t*)ldst, 16, 0, 0);
}

// ---------------- conversion kernels ----------------

__global__ void conv_x_slab(const float* __restrict__ x, __half* __restrict__ xb,
                            int row0, int rows) {
    int idx = blockIdx.x * 256 + threadIdx.x;
    if (idx >= rows * FPAD) return;
    int col = idx % FPAD;
    int r   = idx / FPAD;
    float v = (col < FEAT) ? x[(size_t)(row0 + r) * FEAT + col] : 0.0f;
    xb[idx] = __float2half(v);
}

// W [K,N] fp32 row-major -> Wt [N,Kpad] fp16 row-major (transposed, zero-padded K)
__global__ void conv_wt_kernel(const float* __restrict__ W, __half* __restrict__ Wt,
                               int K, int N, int Kpad) {
    int idx = blockIdx.x * 256 + threadIdx.x;
    if (idx >= N * Kpad) return;
    int k = idx % Kpad;
    int n = idx / Kpad;
    float v = (k < K) ? W[(size_t)k * N + n] : 0.0f;
    Wt[idx] = __float2half(v);
}

// 4x HIDxHID weight transpose+cvt in one dispatch (blockIdx.y selects weight)
__global__ void conv_w4_kernel(const float* __restrict__ W2, const float* __restrict__ W3,
                               const float* __restrict__ W4, const float* __restrict__ W6,
                               __half* __restrict__ w2t, __half* __restrict__ w3t,
                               __half* __restrict__ w4t, __half* __restrict__ w6t) {
    int idx = blockIdx.x * 256 + threadIdx.x;
    if (idx >= HID * HID) return;
    int k = idx % HID;
    int n = idx / HID;
    const float* Ws[4] = {W2, W3, W4, W6};
    __half* Ts[4] = {w2t, w3t, w4t, w6t};
    int w = blockIdx.y;
    Ts[w][idx] = __float2half(Ws[w][(size_t)k * HID + n]);
}

// ---------------- main GEMM: C = act(A @ Bt^T + bias) ----------------
// A [M,K] f16 row-major, Bt [N,K] f16 row-major, C [M,N] f16, bias fp32[N]
// 128x128 tile, BK=32, 256 threads (4 waves), mfma_f32_16x16x32_f16.
// XCD-aware swizzle (bm-space partitioned across 8 XCDs, bn-fast within) +
// LDS-repack epilogue for 16B coalesced C stores.

__global__ __launch_bounds__(256, 2)
void gemm_f16(const __half* __restrict__ A, const __half* __restrict__ Bt,
              __half* __restrict__ C, const float* __restrict__ bias,
              int M, int N, int K, int relu_flag)
{
    __shared__ __align__(16) short smem[128 * 32 * 2];   // 16 KB: staging, then C-tile
    short* lds_a = smem;
    short* lds_b = smem + 128 * 32;

    const int t   = threadIdx.x;
    const int nbn = N >> 7;
    const int nbm = M >> 7;
    int bm, bn;
    {
        const int b = blockIdx.x;
        if ((nbm & 7) == 0) {
            const int xcd = b & 7;
            const int j   = b >> 3;
            bm = xcd * (nbm >> 3) + j / nbn;
            bn = j % nbn;
        } else {
            bn = b % nbn;
            bm = b / nbn;
        }
    }
    const size_t m0 = (size_t)bm * 128;
    const size_t n0 = (size_t)bn * 128;
    const int wave = t >> 6, lane = t & 63;
    const int wm = (wave >> 1) << 6;
    const int wn = (wave & 1) << 6;
    const int l16 = lane & 15, q = lane >> 4;

    floatx4 acc[4][4] = {};

    const int c0 = t, c1 = t + 256;
    const __half* a0 = A  + (m0 + (size_t)(c0 >> 2)) * K + (c0 & 3) * 8;
    const __half* a1 = A  + (m0 + (size_t)(c1 >> 2)) * K + (c1 & 3) * 8;
    const __half* b0 = Bt + (n0 + (size_t)(c0 >> 2)) * K + (c0 & 3) * 8;
    const __half* b1 = Bt + (n0 + (size_t)(c1 >> 2)) * K + (c1 & 3) * 8;
    short* la0 = &lds_a[c0 * 8];
    short* la1 = &lds_a[c1 * 8];
    short* lb0 = &lds_b[c0 * 8];
    short* lb1 = &lds_b[c1 * 8];

    for (int k0 = 0; k0 < K; k0 += 32) {
        __syncthreads();
        async_copy16(a0 + k0, la0);
        async_copy16(a1 + k0, la1);
        async_copy16(b0 + k0, lb0);
        async_copy16(b1 + k0, lb1);
        __syncthreads();

        short8 af[4], bf[4];
#pragma unroll
        for (int i = 0; i < 4; ++i)
            af[i] = *(const short8*)&lds_a[(wm + i * 16 + l16) * 32 + q * 8];
#pragma unroll
        for (int i = 0; i < 4; ++i)
            bf[i] = *(const short8*)&lds_b[(wn + i * 16 + l16) * 32 + q * 8];

#pragma unroll
        for (int mi = 0; mi < 4; ++mi)
#pragma unroll
            for (int ni = 0; ni < 4; ++ni)
                acc[mi][ni] = __builtin_amdgcn_mfma_f32_16x16x32_f16(
                    af[mi], bf[ni], acc[mi][ni], 0, 0, 0);
    }

    // ---- epilogue: two 64-row rounds through LDS, 16B coalesced stores ----
    __half* ct = (__half*)smem;   // 64 rows x 128 cols f16 = 16 KB
#pragma unroll
    for (int h = 0; h < 2; ++h) {
        __syncthreads();          // staging/previous-round reads done
        if (wm == h * 64) {
#pragma unroll
            for (int ni = 0; ni < 4; ++ni) {
                const int col = wn + ni * 16 + l16;
                const float bv = bias[n0 + col];
#pragma unroll
                for (int mi = 0; mi < 4; ++mi) {
                    const int r0l = mi * 16 + q * 4;
#pragma unroll
                    for (int r = 0; r < 4; ++r) {
                        float v = acc[mi][ni][r] + bv;
                        if (relu_flag) v = fmaxf(v, 0.0f);
                        ct[(r0l + r) * 128 + col] = __float2half(v);
                    }
                }
            }
        }
        __syncthreads();
#pragma unroll
        for (int it = 0; it < 4; ++it) {
            const int chunk = it * 256 + t;        // 1024 chunks of 16B
            const int row = chunk >> 4;            // 16 chunks per 128-col row
            const int off = (chunk & 15) * 8;      // halves
            *(short8*)&C[(m0 + h * 64 + row) * N + n0 + off] =
                *(const short8*)&ct[row * 128 + off];
        }
    }
}

// ---------------- segment offsets ----------------

__global__ void seg_offsets_kernel(const int* __restrict__ lengths, int* __restrict__ off) {
    if (blockIdx.x == 0 && threadIdx.x == 0) {
        int a = 0;
        off[0] = 0;
        for (int i = 0; i < SEGN; ++i) { a += lengths[i]; off[i + 1] = a; }
    }
}

// ---------------- e-scores: e_f = exp(relu(h4_f . W5 + b5)) -------------------

__global__ __launch_bounds__(256)
void escore_kernel(const __half* __restrict__ h4, int slab_beg,
                   const float* __restrict__ W5, const float* __restrict__ b5,
                   float* __restrict__ earr)
{
    const int fl   = blockIdx.x * 4 + (threadIdx.x >> 6);
    const int lane = threadIdx.x & 63;
    const __half* row = h4 + (size_t)fl * HID + lane * 16;
    const float*  wv  = W5 + lane * 16;

    short8 r0 = *(const short8*)row;
    short8 r1 = *(const short8*)(row + 8);
    float s = 0.f;
#pragma unroll
    for (int j = 0; j < 8; ++j) s += __half2float(((const __half*)&r0)[j]) * wv[j];
#pragma unroll
    for (int j = 0; j < 8; ++j) s += __half2float(((const __half*)&r1)[j]) * wv[j + 8];
#pragma unroll
    for (int o = 32; o > 0; o >>= 1) s += __shfl_down(s, o);
    if (lane == 0)
        earr[slab_beg + fl] = __expf(fminf(fmaxf(s + b5[0], 0.0f), 80.0f));
}

// ---------------- pooling accumulate: frame-chunk parallel --------------------

__global__ __launch_bounds__(256)
void pool_accum_kernel(const __half* __restrict__ h4, int slab_beg,
                       const float* __restrict__ earr, const int* __restrict__ segoff,
                       float* __restrict__ pooled)
{
    const int c0 = blockIdx.y * 512 + threadIdx.x * 2;
    const int f0 = slab_beg + blockIdx.x * FCHUNK;
    const int fend = f0 + FCHUNK;

    int lo = 0, hi = SEGN - 1;
    while (lo < hi) {
        int mid = (lo + hi + 1) >> 1;
        if (segoff[mid] <= f0) lo = mid; else hi = mid - 1;
    }
    int s = lo;

    const __half* base = h4 + (size_t)(f0 - slab_beg) * HID + c0;
    int f = f0;
    while (f < fend) {
        int send = segoff[s + 1];
        if (send > fend) send = fend;
        float a0 = 0.f, a1 = 0.f;
        for (; f < send; ++f, base += HID) {
            float e = earr[f];
            float2 fv = __half22float2(*(const __half2*)base);
            a0 += e * fv.x;
            a1 += e * fv.y;
        }
        float* p = pooled + (size_t)s * HID + c0;
        atomicAdd(p, a0);
        atomicAdd(p + 1, a1);
        ++s;
    }
}

// ---------------- finalize: denom reduce + divide + fp16 ----------------------

__global__ __launch_bounds__(256)
void finalize_pool_kernel(const float* __restrict__ pooled, const float* __restrict__ earr,
                          const int* __restrict__ segoff, __half* __restrict__ poolh)
{
    int s = blockIdx.x, t = threadIdx.x;
    int beg = segoff[s], end = segoff[s + 1];
    __shared__ float sh[4];
    float es = 0.f;
    for (int i = beg + t; i < end; i += 256) es += earr[i];
#pragma unroll
    for (int o = 32; o > 0; o >>= 1) es += __shfl_down(es, o);
    if ((t & 63) == 0) sh[t >> 6] = es;
    __syncthreads();
    float inv = 1.0f / (sh[0] + sh[1] + sh[2] + sh[3]);
    for (int j = t; j < HID; j += 256)
        poolh[(size_t)s * HID + j] = __float2half(pooled[(size_t)s * HID + j] * inv);
}

// ---------------- final head: out = z @ W7 + b7 ----------------

__global__ void final_kernel(const __half* __restrict__ z, const float* __restrict__ W7,
                             const float* __restrict__ b7, float* __restrict__ out) {
    int s = blockIdx.x, t = threadIdx.x;
    float loc[NCLS];
#pragma unroll
    for (int c = 0; c < NCLS; ++c) loc[c] = 0.f;
    for (int k = t; k < HID; k += 256) {
        float zk = __half2float(z[(size_t)s * HID + k]);
        const float* wr = W7 + k * NCLS;
#pragma unroll
        for (int c = 0; c < NCLS; ++c) loc[c] += zk * wr[c];
    }
#pragma unroll
    for (int c = 0; c < NCLS; ++c)
#pragma unroll
        for (int o = 32; o > 0; o >>= 1) loc[c] += __shfl_down(loc[c], o);
    __shared__ float accs[NCLS];
    if (t < NCLS) accs[t] = 0.f;
    __syncthreads();
    if ((t & 63) == 0)
        for (int c = 0; c < NCLS; ++c) atomicAdd(&accs[c], loc[c]);
    __syncthreads();
    if (t < NCLS) out[s * NCLS + t] = accs[t] + b7[t];
}

// ---------------- launch ----------------

extern "C" void kernel_launch(void* const* d_in, const int* in_sizes, int n_in,
                              void* d_out, int out_size, void* d_ws, size_t ws_size,
                              hipStream_t stream) {
    const float* x  = (const float*)d_in[0];
    const float* W1 = (const float*)d_in[1];
    const float* b1 = (const float*)d_in[2];
    const float* W2 = (const float*)d_in[3];
    const float* b2 = (const float*)d_in[4];
    const float* W3 = (const float*)d_in[5];
    const float* b3 = (const float*)d_in[6];
    const float* W4 = (const float*)d_in[7];
    const float* b4 = (const float*)d_in[8];
    const float* W5 = (const float*)d_in[9];
    const float* b5 = (const float*)d_in[10];
    const float* W6 = (const float*)d_in[11];
    const float* b6 = (const float*)d_in[12];
    const float* W7 = (const float*)d_in[13];
    const float* b7 = (const float*)d_in[14];
    const int* lengths = (const int*)d_in[15];
    float* out = (float*)d_out;

    char* ws = (char*)d_ws;
    size_t off = 0;
    auto take = [&](size_t bytes) -> char* {
        char* p = ws + off;
        off = (off + bytes + 255) & ~(size_t)255;
        return p;
    };
    __half* w1t   = (__half*)take((size_t)HID * FPAD * 2);
    __half* w2t   = (__half*)take((size_t)HID * HID * 2);
    __half* w3t   = (__half*)take((size_t)HID * HID * 2);
    __half* w4t   = (__half*)take((size_t)HID * HID * 2);
    __half* w6t   = (__half*)take((size_t)HID * HID * 2);
    int*    segoff = (int*)take((SEGN + 1) * 4);
    float*  pooled = (float*)take((size_t)SEGN * HID * 4);
    __half* poolh  = (__half*)take((size_t)SEGN * HID * 2);
    __half* z      = (__half*)take((size_t)SEGN * HID * 2);
    float*  earr   = (float*)take((size_t)TOTAL * 4);

    int R = TOTAL;
    while (R > 1024) {
        size_t need = off + (size_t)R * FPAD * 2 + 2 * (size_t)R * HID * 2 + 3 * 256;
        if (need <= ws_size) break;
        R >>= 1;
    }
    __half* slabX = (__half*)take((size_t)R * FPAD * 2);
    __half* slabA = (__half*)take((size_t)R * HID * 2);
    __half* slabB = (__half*)take((size_t)R * HID * 2);

    seg_offsets_kernel<<<1, 64, 0, stream>>>(lengths, segoff);
    hipMemsetAsync(pooled, 0, (size_t)SEGN * HID * 4, stream);

    conv_wt_kernel<<<(HID * FPAD + 255) / 256, 256, 0, stream>>>(W1, w1t, FEAT, HID, FPAD);
    dim3 gW((HID * HID + 255) / 256, 4);
    conv_w4_kernel<<<gW, 256, 0, stream>>>(W2, W3, W4, W6, w2t, w3t, w4t, w6t);

    const int nBlocksSlab = (R / 128) * (HID / 128);
    dim3 gPool(R / FCHUNK, 2);
    for (int sb = 0; sb < TOTAL; sb += R) {
        conv_x_slab<<<(R * FPAD + 255) / 256, 256, 0, stream>>>(x, slabX, sb, R);
        gemm_f16<<<nBlocksSlab, 256, 0, stream>>>(slabX, w1t, slabA, b1, R, HID, FPAD, 1);
        gemm_f16<<<nBlocksSlab, 256, 0, stream>>>(slabA, w2t, slabB, b2, R, HID, HID, 1);
        gemm_f16<<<nBlocksSlab, 256, 0, stream>>>(slabB, w3t, slabA, b3, R, HID, HID, 1);
        gemm_f16<<<nBlocksSlab, 256, 0, stream>>>(slabA, w4t, slabB, b4, R, HID, HID, 1);
        escore_kernel<<<R / 4, 256, 0, stream>>>(slabB, sb, W5, b5, earr);
        pool_accum_kernel<<<gPool, 256, 0, stream>>>(slabB, sb, earr, segoff, pooled);
    }

    finalize_pool_kernel<<<SEGN, 256, 0, stream>>>(pooled, earr, segoff, poolh);
    const int nBlocksHead = (SEGN / 128) * (HID / 128);
    gemm_f16<<<nBlocksHead, 256, 0, stream>>>(poolh, w6t, z, b6, SEGN, HID, HID, 1);
    final_kernel<<<SEGN, 256, 0, stream>>>(z, W7, b7, out);
}